// Round 2
// baseline (396.663 us; speedup 1.0000x reference)
//
#include <hip/hip_runtime.h>
#include <math.h>

// JointDecoder: depth_logits (B=2,D=128,H=256,W=256) f32, bev (B,2,128,128),
// inv_K (B,4,4) -> out (B,H,W,D,3) f32.
#define DD   128
#define HH   256
#define WW   256
#define HW   (HH * WW)
#define BEVN 16384
#define LOG3 (-1.0986f)

// ---------------- Kernel A: interleaved log class-prob table [cell][3] -------
__global__ void jd_logcp_kernel(const float* __restrict__ bev,
                                float* __restrict__ logcp, int B) {
    int i = blockIdx.x * blockDim.x + threadIdx.x;
    if (i >= B * BEVN) return;
    int b  = i >> 14;
    int zx = i & (BEVN - 1);
    float x0 = bev[(b * 2 + 0) * BEVN + zx];
    float x1 = bev[(b * 2 + 1) * BEVN + zx];
    const float LO = 1e-7f;
    const float HI = (float)(1.0 - 1e-7);
    float p0 = fminf(fmaxf(1.0f / (1.0f + expf(-x0)), LO), HI);
    float p1 = fminf(fmaxf(1.0f / (1.0f + expf(-x1)), LO), HI);
    float* o = logcp + ((size_t)b * BEVN + zx) * 3;
    o[0] = logf(1.0f - p1);
    o[1] = logf(p1 * p0);
    o[2] = logf(p1 * (1.0f - p0));
}

// ---------------- Kernel B: softmax + lift + combine -------------------------
// Block: 256 threads = 4 waves, handles (b, h, 64 w's, all 128 d).
// Phase 1: lane=w, wave q owns d in [32q,32q+32): coalesced strided loads,
//          cross-wave LDS reduce; depth log-probs stay in v[32] registers.
// Phase 2: lane=w (gathers nearly contiguous: vz lane-uniform, vx step ~0.23*dval),
//          stage 4-d sub-chunks in wave-private padded LDS, store float4 runs.
__global__ __launch_bounds__(256) void jd_main_kernel(
        const float* __restrict__ depth, const float* __restrict__ invK,
        const float* __restrict__ logcp, float* __restrict__ out) {
    __shared__ float stg[4 * 13 * 64];   // per-wave 64 pixels x 13 (12 used, +1 pad)
    __shared__ float pmax[256];
    __shared__ float psum[256];

    const int t    = threadIdx.x;
    const int lane = t & 63;
    const int q    = t >> 6;
    const int bid  = blockIdx.x;
    const int w0   = (bid & 3) * 64;
    const int h    = (bid >> 2) & (HH - 1);
    const int b    = bid >> 10;
    const int dbase = q * 32;

    // ---- Phase 1: log_softmax over d, lane = w ----
    const float* dp = depth + (size_t)b * DD * HW + (size_t)h * WW + w0 + lane;
    float v[32];
    float m = -INFINITY;
#pragma unroll
    for (int i = 0; i < 32; ++i) {
        v[i] = dp[(size_t)(dbase + i) * HW];   // 64 consecutive floats per wave
        m = fmaxf(m, v[i]);
    }
    pmax[t] = m;
    __syncthreads();
    float mm = fmaxf(fmaxf(pmax[lane], pmax[64 + lane]),
                     fmaxf(pmax[128 + lane], pmax[192 + lane]));
    float s = 0.0f;
#pragma unroll
    for (int i = 0; i < 32; ++i) s += expf(v[i] - mm);
    psum[t] = s;
    __syncthreads();
    float S  = ((psum[lane] + psum[64 + lane]) + psum[128 + lane]) + psum[192 + lane];
    float lS = logf(S);
#pragma unroll
    for (int i = 0; i < 32; ++i) v[i] = (v[i] - mm) - lS;   // final depth log-prob

    // ---- Phase 2 ----
    const float* ik = invK + b * 16;
    const float yf = (float)h;
    const float xf = (float)(w0 + lane);
    // einsum order: ik_i0*x + ik_i1*y + ik_i2, round-to-nearest each step, no FMA
    const float camx = __fadd_rn(__fadd_rn(__fmul_rn(ik[0], xf), __fmul_rn(ik[1], yf)), ik[2]);
    const float camy = __fadd_rn(__fadd_rn(__fmul_rn(ik[4], xf), __fmul_rn(ik[5], yf)), ik[6]);
    const float camz = __fadd_rn(__fadd_rn(__fmul_rn(ik[8], xf), __fmul_rn(ik[9], yf)), ik[10]);

    const float* cp3 = logcp + (size_t)b * BEVN * 3;
    float* wstg = stg + q * (13 * 64);
    const size_t pixbase0 = ((size_t)b * HW + (size_t)h * WW + w0) * (DD * 3);

    // Store-lane precompute: float4 index g = k*64+lane -> pixel w2, sub-chunk slot kk
    int   ldsa[3];
    size_t ga[3];
#pragma unroll
    for (int k = 0; k < 3; ++k) {
        int g  = k * 64 + lane;
        int ww = g / 3;
        int kk = g - ww * 3;
        ldsa[k] = ww * 13 + kk * 4;
        ga[k]   = pixbase0 + (size_t)ww * (DD * 3) + (size_t)dbase * 3 + kk * 4;
    }

    const double stepd = (3.2875 - 0.1125) / 127.0;   // np.linspace step in f64

    for (int sc = 0; sc < 8; ++sc) {
#pragma unroll
        for (int j = 0; j < 4; ++j) {
            const int i = sc * 4 + j;
            const int d = dbase + i;
            const float dval = (d == 127) ? (float)3.2875
                                          : (float)((double)d * stepd + 0.1125);
            float px = __fmul_rn(dval, camx);
            float py = __fmul_rn(dval, camy);
            float pz = __fmul_rn(dval, camz);
            py = -py; pz = -pz;                      // * [1,-1,-1]
            const float tx = __fsub_rn(px, -1.6f);   // - CAM_OFFSET
            const float ty = __fsub_rn(py, 0.0f);
            const float tz = __fsub_rn(pz, -3.3f);
            const int vx = (int)__fdiv_rn(tx, 0.025f);
            const int vy = (int)__fdiv_rn(ty, 0.025f);
            const int vz = (int)__fdiv_rn(tz, 0.025f);
            const bool valid = (vx >= 0) & (vx < 128) & (vz >= 0) & (vz < 128) & (vy <= 0);
            const int base = valid ? (vz * 128 + vx) : 0;   // safe_base, no divergence
            const float* l = cp3 + base * 3;                // dwordx3, ~3-10 lines/wave
            const float l0 = l[0], l1 = l[1], l2 = l[2];
            const float dlp = v[i];
            wstg[lane * 13 + j * 3 + 0] = __fadd_rn(valid ? l0 : LOG3, dlp);
            wstg[lane * 13 + j * 3 + 1] = __fadd_rn(valid ? l1 : LOG3, dlp);
            wstg[lane * 13 + j * 3 + 2] = __fadd_rn(valid ? l2 : LOG3, dlp);
        }
        // wave-private staging: LDS is in-order per wave; fence = compiler order +
        // lgkmcnt only (workgroup scope, no vmcnt drain / no s_barrier)
        __builtin_amdgcn_fence(__ATOMIC_ACQ_REL, "workgroup");
#pragma unroll
        for (int k = 0; k < 3; ++k) {
            float4 val;
            val.x = wstg[ldsa[k] + 0];
            val.y = wstg[ldsa[k] + 1];
            val.z = wstg[ldsa[k] + 2];
            val.w = wstg[ldsa[k] + 3];
            *(float4*)(out + ga[k] + sc * 12) = val;   // 48B/pixel runs, 16B aligned
        }
        __builtin_amdgcn_fence(__ATOMIC_ACQ_REL, "workgroup");
    }
}

extern "C" void kernel_launch(void* const* d_in, const int* in_sizes, int n_in,
                              void* d_out, int out_size, void* d_ws, size_t ws_size,
                              hipStream_t stream) {
    const float* depth = (const float*)d_in[0];
    const float* bev   = (const float*)d_in[1];
    const float* invK  = (const float*)d_in[2];
    float* out   = (float*)d_out;
    float* logcp = (float*)d_ws;   // B*16384*3 floats = 384 KB, re-written every call

    const int B = in_sizes[0] / (DD * HW);   // = 2

    jd_logcp_kernel<<<(B * BEVN + 255) / 256, 256, 0, stream>>>(bev, logcp, B);
    jd_main_kernel<<<B * HH * (WW / 64), 256, 0, stream>>>(depth, invK, logcp, out);
}

// Round 3
// 267.665 us; speedup vs baseline: 1.4819x; 1.4819x over previous
//
#include <hip/hip_runtime.h>
#include <math.h>

// JointDecoder: depth_logits (B=2,D=128,H=256,W=256) f32, bev (B,2,128,128),
// inv_K (B,4,4) -> out (B,H,W,D,3) f32.
#define DD   128
#define HH   256
#define WW   256
#define HW   (HH * WW)
#define BEVN 16384
#define LOG3 (-1.0986f)
#define STRIDE 97          // lbuf row stride in floats (96 data + 1 pad, odd -> 2-way banks)

// ---------------- Kernel A: log class-prob table, float4-interleaved ---------
__global__ void jd_logcp_kernel(const float* __restrict__ bev,
                                float4* __restrict__ logcp, int B) {
    int i = blockIdx.x * blockDim.x + threadIdx.x;
    if (i >= B * BEVN) return;
    int b  = i >> 14;
    int zx = i & (BEVN - 1);
    float x0 = bev[(b * 2 + 0) * BEVN + zx];
    float x1 = bev[(b * 2 + 1) * BEVN + zx];
    const float LO = 1e-7f;
    const float HI = (float)(1.0 - 1e-7);
    float p0 = fminf(fmaxf(1.0f / (1.0f + expf(-x0)), LO), HI);
    float p1 = fminf(fmaxf(1.0f / (1.0f + expf(-x1)), LO), HI);
    float4 o;
    o.x = logf(1.0f - p1);
    o.y = logf(p1 * p0);
    o.z = logf(p1 * (1.0f - p0));
    o.w = 0.0f;
    logcp[(size_t)b * BEVN + zx] = o;   // 16B/lane coalesced
}

// ---------------- Kernel B: softmax + lift + combine, barrier-free -----------
// Block = 4 independent waves. Wave q owns pixels w in [w0+16q, w0+16q+16),
// all 128 d. Lane = (wl = lane&15 -> pixel, dj = lane>>4 -> d mod 4).
// Phase 1: 32 strided loads/lane (4-seg coalesced), softmax via shfl_xor only.
// Phase 2 per 32-d chunk: gather (lane-w-major: ~2 lines per dj-group, table is
// L2-resident), combine with register dlp, stage to wave-private LDS slab in
// output order, then 6 float4 stores/lane = 64B-aligned 384B runs. No barriers;
// same-wave DS ops execute in order.
__global__ __launch_bounds__(256) void jd_main_kernel(
        const float* __restrict__ depth, const float* __restrict__ invK,
        const float4* __restrict__ logcp, float* __restrict__ out) {
    __shared__ float lbuf[4 * 16 * STRIDE];   // 24.8 KB, wave-private quarters

    const int t    = threadIdx.x;
    const int lane = t & 63;
    const int q    = t >> 6;
    const int wl   = lane & 15;
    const int dj   = lane >> 4;
    const int bid  = blockIdx.x;
    const int w0   = (bid & 3) * 64;
    const int h    = (bid >> 2) & (HH - 1);
    const int b    = bid >> 10;
    const int w    = w0 + q * 16 + wl;

    // ---- Phase 1: log_softmax over d for this lane's pixel, d = 4i + dj ----
    const float* dp = depth + (size_t)b * DD * HW + (size_t)h * WW + w;
    float v[32];
    float m = -INFINITY;
#pragma unroll
    for (int i = 0; i < 32; ++i) {
        v[i] = dp[(size_t)(4 * i + dj) * HW];   // 4 segs x 64B per instr
        m = fmaxf(m, v[i]);
    }
    m = fmaxf(m, __shfl_xor(m, 16));
    m = fmaxf(m, __shfl_xor(m, 32));
    float s = 0.0f;
#pragma unroll
    for (int i = 0; i < 32; ++i) s += expf(v[i] - m);
    s += __shfl_xor(s, 16);
    s += __shfl_xor(s, 32);
    const float lS = logf(s);
#pragma unroll
    for (int i = 0; i < 32; ++i) v[i] = (v[i] - m) - lS;   // final depth log-prob

    // ---- cam ray for this lane's pixel (einsum order, no FMA contraction) ----
    const float* ik = invK + b * 16;
    const float yf = (float)h, xf = (float)w;
    const float camx = __fadd_rn(__fadd_rn(__fmul_rn(ik[0], xf), __fmul_rn(ik[1], yf)), ik[2]);
    const float camy = __fadd_rn(__fadd_rn(__fmul_rn(ik[4], xf), __fmul_rn(ik[5], yf)), ik[6]);
    const float camz = __fadd_rn(__fadd_rn(__fmul_rn(ik[8], xf), __fmul_rn(ik[9], yf)), ik[10]);

    const float4* cp4 = logcp + (size_t)b * BEVN;
    float* wbuf = lbuf + q * (16 * STRIDE);

    // store-lane precompute: float4 f = k*64+lane -> (pixel ww, slot ss)
    int ldsoff[6];
    size_t goff[6];
    const size_t gbase = ((size_t)b * HW + (size_t)h * WW + (w0 + q * 16)) * (DD * 3);
#pragma unroll
    for (int k = 0; k < 6; ++k) {
        int f  = k * 64 + lane;
        int ww = f / 24;            // 24 float4 per pixel per chunk
        int ss = f - ww * 24;
        ldsoff[k] = ww * STRIDE + ss * 4;
        goff[k]   = gbase + (size_t)ww * (DD * 3) + ss * 4;
    }

    const double stepd = (3.2875 - 0.1125) / 127.0;   // np.linspace step (f64)

    for (int c = 0; c < 4; ++c) {
        // -- gather + combine: this wave's 16 px x 32 d of the chunk --
#pragma unroll
        for (int i2 = 0; i2 < 8; ++i2) {
            const int dl = 4 * i2 + dj;
            const int d  = 32 * c + dl;
            const float dval = (d == 127) ? (float)3.2875
                                          : (float)((double)d * stepd + 0.1125);
            float px = __fmul_rn(dval, camx);
            float py = __fmul_rn(dval, camy);
            float pz = __fmul_rn(dval, camz);
            py = -py; pz = -pz;                      // * [1,-1,-1]
            const float tx = __fsub_rn(px, -1.6f);   // - CAM_OFFSET
            const float ty = __fsub_rn(py, 0.0f);
            const float tz = __fsub_rn(pz, -3.3f);
            const int vx = (int)__fdiv_rn(tx, 0.025f);
            const int vy = (int)__fdiv_rn(ty, 0.025f);
            const int vz = (int)__fdiv_rn(tz, 0.025f);
            const bool valid = (vx >= 0) & (vx < 128) & (vz >= 0) & (vz < 128) & (vy <= 0);
            const int base = valid ? (vz * 128 + vx) : 0;   // safe_base
            const float4 l = cp4[base];                     // single dwordx4, L2-hit
            const float dlp = v[8 * c + i2];
            float* wp = wbuf + wl * STRIDE + dl * 3;        // banks (wl+..)%32: 2-way free
            wp[0] = __fadd_rn(valid ? l.x : LOG3, dlp);
            wp[1] = __fadd_rn(valid ? l.y : LOG3, dlp);
            wp[2] = __fadd_rn(valid ? l.z : LOG3, dlp);
        }
        // -- drain slab to global: 64B-aligned 384B runs, no amplification --
        // (same-wave DS pipe is in-order; no barrier / no fence needed)
#pragma unroll
        for (int k = 0; k < 6; ++k) {
            const int la = ldsoff[k];
            float4 o;
            o.x = wbuf[la + 0];
            o.y = wbuf[la + 1];
            o.z = wbuf[la + 2];
            o.w = wbuf[la + 3];
            *(float4*)(out + goff[k] + c * 96) = o;
        }
    }
}

extern "C" void kernel_launch(void* const* d_in, const int* in_sizes, int n_in,
                              void* d_out, int out_size, void* d_ws, size_t ws_size,
                              hipStream_t stream) {
    const float* depth = (const float*)d_in[0];
    const float* bev   = (const float*)d_in[1];
    const float* invK  = (const float*)d_in[2];
    float* out    = (float*)d_out;
    float4* logcp = (float4*)d_ws;   // B*16384 float4 = 512 KB, rewritten every call

    const int B = in_sizes[0] / (DD * HW);   // = 2

    jd_logcp_kernel<<<(B * BEVN + 255) / 256, 256, 0, stream>>>(bev, logcp, B);
    jd_main_kernel<<<B * HH * (WW / 64), 256, 0, stream>>>(depth, invK, logcp, out);
}